// Round 7
// baseline (41.695 us; speedup 1.0000x reference)
//
#include <hip/hip_runtime.h>

#define MAX_OFFSET_C 0.05f
#define EPS_C 1e-6f

typedef float f32x4 __attribute__((ext_vector_type(4)));

__device__ __forceinline__ float fexp_fast(float c, float p) {
    // sign(c) * |c|^p ; at c==0, exp2(p * -inf) = 0 -> matches jnp
    float r = __builtin_amdgcn_exp2f(p * __log2f(fabsf(c)));
    return copysignf(r, c);
}

__device__ __forceinline__ float clamp_signed(float v) {
    // reference: sgn = where(v>0, 1, -1); sgn * max(|v|, EPS)
    float sgn = (v > 0.f) ? 1.f : -1.f;
    return sgn * fmaxf(fabsf(v), EPS_C);
}

__device__ __forceinline__ float fast_tanh(float x) {
    x = fminf(fmaxf(x, -15.f), 15.f);   // avoid inf/inf
    float e = __expf(2.f * x);
    return 1.f - 2.f / (e + 1.f);
}

// 4 points per thread (measured optimum: R2/R6 39us; 8pt 52us, NT stores 46us).
// Grid-stride with 2048 persistent blocks (G11): waves stay resident instead
// of 6400 launch/drain workgroups — attacks the measured latency-bound gap
// (Occupancy 68%, VALUBusy 31%, HBM 60% of ceiling).
__global__ __launch_bounds__(256) void superq_kernel(
    const float* __restrict__ sqscale,      // (S,3)
    const float* __restrict__ exponents,    // (S,2)
    const float* __restrict__ translation,  // (S,3)
    const float* __restrict__ rotation,     // (S,3,3)
    const float* __restrict__ etas,         // (S,N)
    const float* __restrict__ omegas,       // (S,N)
    const float* __restrict__ offsets,      // (Ng,3)
    const unsigned char* __restrict__ is_prune, // (Ng,) bool
    float* __restrict__ out,                // (Ng,3)
    int n_groups)                           // Ng/4
{
    const int stride = gridDim.x * blockDim.x;
    for (int g = blockIdx.x * blockDim.x + threadIdx.x; g < n_groups; g += stride) {
        const int base = g * 4;         // global point index of first of 4

        // stream loads first — in flight during index math + param loads
        const f32x4 et = *reinterpret_cast<const f32x4*>(etas  + base);
        const f32x4 om = *reinterpret_cast<const f32x4*>(omegas + base);
        f32x4 offv[3];
        {
            const f32x4* offp = reinterpret_cast<const f32x4*>(offsets + (size_t)base * 3);
            offv[0] = offp[0]; offv[1] = offp[1]; offv[2] = offp[2];
        }
        const float* offs = reinterpret_cast<const float*>(offv);

        uchar4 pr4 = *reinterpret_cast<const uchar4*>(is_prune + base);
        const unsigned char prc[4] = {pr4.x, pr4.y, pr4.z, pr4.w};

        const int s = g / 100;          // 100 groups-of-4 per s (N=400)

        // per-s params (broadcast through L1; 1-2 distinct s per wave)
        const float a1 = sqscale[3*s+0], a2 = sqscale[3*s+1], a3 = sqscale[3*s+2];
        const float e1 = exponents[2*s+0], e2 = exponents[2*s+1];
        float R[9];
        #pragma unroll
        for (int k = 0; k < 9; ++k) R[k] = rotation[9*s + k];
        const float t0 = translation[3*s+0], t1 = translation[3*s+1], t2 = translation[3*s+2];

        const float ev[4] = {et.x, et.y, et.z, et.w};
        const float ov[4] = {om.x, om.y, om.z, om.w};

        float res[12];
        #pragma unroll
        for (int k = 0; k < 4; ++k) {
            const float eta = ev[k], omg = ov[k];
            const float ce1 = fexp_fast(__cosf(eta), e1);
            const float se1 = fexp_fast(__sinf(eta), e1);
            const float co2 = fexp_fast(__cosf(omg), e2);
            const float so2 = fexp_fast(__sinf(omg), e2);

            const float x = clamp_signed(a1 * ce1 * co2);
            const float y = clamp_signed(a2 * ce1 * so2);
            const float z = clamp_signed(a3 * se1);

            // einsum 'snd,sed->sne': g[e] = sum_d pos[d] * R[e][d]
            float g0 = x*R[0] + y*R[1] + z*R[2] + t0;
            float g1 = x*R[3] + y*R[4] + z*R[5] + t1;
            float g2 = x*R[6] + y*R[7] + z*R[8] + t2;

            g0 += fast_tanh(offs[3*k+0]) * MAX_OFFSET_C;
            g1 += fast_tanh(offs[3*k+1]) * MAX_OFFSET_C;
            g2 += fast_tanh(offs[3*k+2]) * MAX_OFFSET_C;

            if (prc[k]) { g0 = 0.f; g1 = 0.f; g2 = 0.f; }
            res[3*k+0] = g0; res[3*k+1] = g1; res[3*k+2] = g2;
        }

        f32x4* outp = reinterpret_cast<f32x4*>(out + (size_t)base * 3);
        const f32x4* resv = reinterpret_cast<const f32x4*>(res);
        outp[0] = resv[0];
        outp[1] = resv[1];
        outp[2] = resv[2];
    }
}

extern "C" void kernel_launch(void* const* d_in, const int* in_sizes, int n_in,
                              void* d_out, int out_size, void* d_ws, size_t ws_size,
                              hipStream_t stream) {
    const float* sqscale     = (const float*)d_in[0];
    const float* exponents   = (const float*)d_in[1];
    const float* translation = (const float*)d_in[2];
    const float* rotation    = (const float*)d_in[3];
    const float* etas        = (const float*)d_in[4];
    const float* omegas      = (const float*)d_in[5];
    const float* offsets     = (const float*)d_in[6];
    const unsigned char* is_prune = (const unsigned char*)d_in[7];
    float* out = (float*)d_out;

    const int Ng = in_sizes[7];          // S*N points
    const int n_groups = Ng / 4;         // 4 points per thread
    const int block = 256;
    const int grid = 2048;               // persistent blocks, grid-stride (G11)

    superq_kernel<<<grid, block, 0, stream>>>(
        sqscale, exponents, translation, rotation,
        etas, omegas, offsets, is_prune, out, n_groups);
}

// Round 8
// 38.241 us; speedup vs baseline: 1.0903x; 1.0903x over previous
//
#include <hip/hip_runtime.h>

#define MAX_OFFSET_C 0.05f
#define EPS_C 1e-6f

typedef float f32x2 __attribute__((ext_vector_type(2)));

__device__ __forceinline__ float fexp_fast(float c, float p) {
    // sign(c) * |c|^p ; at c==0, exp2(p * -inf) = 0 -> matches jnp
    float r = __builtin_amdgcn_exp2f(p * __log2f(fabsf(c)));
    return copysignf(r, c);
}

__device__ __forceinline__ float clamp_signed(float v) {
    // reference: sgn = where(v>0, 1, -1); sgn * max(|v|, EPS)
    float sgn = (v > 0.f) ? 1.f : -1.f;
    return sgn * fmaxf(fabsf(v), EPS_C);
}

__device__ __forceinline__ float fast_tanh(float x) {
    x = fminf(fmaxf(x, -15.f), 15.f);   // avoid inf/inf
    float e = __expf(2.f * x);
    return 1.f - 2.f / (e + 1.f);
}

// 2 points per thread — final probe on the granularity curve
// (8pt: 51.9us, 4pt: 39.1us, 2pt: ?). Mechanism: 2x waves, shorter per-wave
// dependency chain, 128-point wave footprint. Same byte counts, f32x2 I/O.
__global__ __launch_bounds__(256) void superq_kernel(
    const float* __restrict__ sqscale,      // (S,3)
    const float* __restrict__ exponents,    // (S,2)
    const float* __restrict__ translation,  // (S,3)
    const float* __restrict__ rotation,     // (S,3,3)
    const float* __restrict__ etas,         // (S,N)
    const float* __restrict__ omegas,       // (S,N)
    const float* __restrict__ offsets,      // (Ng,3)
    const unsigned char* __restrict__ is_prune, // (Ng,) bool
    float* __restrict__ out,                // (Ng,3)
    int n_groups)                           // Ng/2
{
    int g = blockIdx.x * blockDim.x + threadIdx.x;
    if (g >= n_groups) return;

    const int base = g * 2;         // global point index of first of 2

    // stream loads first — in flight during index math + param loads
    const f32x2 et = *reinterpret_cast<const f32x2*>(etas   + base);
    const f32x2 om = *reinterpret_cast<const f32x2*>(omegas + base);
    f32x2 offv[3];
    {
        const f32x2* offp = reinterpret_cast<const f32x2*>(offsets + (size_t)base * 3);
        offv[0] = offp[0]; offv[1] = offp[1]; offv[2] = offp[2];
    }
    const float* offs = reinterpret_cast<const float*>(offv);

    const uchar2 pr2 = *reinterpret_cast<const uchar2*>(is_prune + base);
    const unsigned char prc[2] = {pr2.x, pr2.y};

    const int s = g / 200;          // 200 groups-of-2 per s (N=400)

    // per-s params (broadcast through L1; 1-2 distinct s per wave)
    const float a1 = sqscale[3*s+0], a2 = sqscale[3*s+1], a3 = sqscale[3*s+2];
    const float e1 = exponents[2*s+0], e2 = exponents[2*s+1];
    float R[9];
    #pragma unroll
    for (int k = 0; k < 9; ++k) R[k] = rotation[9*s + k];
    const float t0 = translation[3*s+0], t1 = translation[3*s+1], t2 = translation[3*s+2];

    const float ev[2] = {et.x, et.y};
    const float ov[2] = {om.x, om.y};

    float res[6];
    #pragma unroll
    for (int k = 0; k < 2; ++k) {
        const float eta = ev[k], omg = ov[k];
        const float ce1 = fexp_fast(__cosf(eta), e1);
        const float se1 = fexp_fast(__sinf(eta), e1);
        const float co2 = fexp_fast(__cosf(omg), e2);
        const float so2 = fexp_fast(__sinf(omg), e2);

        const float x = clamp_signed(a1 * ce1 * co2);
        const float y = clamp_signed(a2 * ce1 * so2);
        const float z = clamp_signed(a3 * se1);

        // einsum 'snd,sed->sne': g[e] = sum_d pos[d] * R[e][d]
        float g0 = x*R[0] + y*R[1] + z*R[2] + t0;
        float g1 = x*R[3] + y*R[4] + z*R[5] + t1;
        float g2 = x*R[6] + y*R[7] + z*R[8] + t2;

        g0 += fast_tanh(offs[3*k+0]) * MAX_OFFSET_C;
        g1 += fast_tanh(offs[3*k+1]) * MAX_OFFSET_C;
        g2 += fast_tanh(offs[3*k+2]) * MAX_OFFSET_C;

        if (prc[k]) { g0 = 0.f; g1 = 0.f; g2 = 0.f; }
        res[3*k+0] = g0; res[3*k+1] = g1; res[3*k+2] = g2;
    }

    f32x2* outp = reinterpret_cast<f32x2*>(out + (size_t)base * 3);
    const f32x2* resv = reinterpret_cast<const f32x2*>(res);
    outp[0] = resv[0];
    outp[1] = resv[1];
    outp[2] = resv[2];
}

extern "C" void kernel_launch(void* const* d_in, const int* in_sizes, int n_in,
                              void* d_out, int out_size, void* d_ws, size_t ws_size,
                              hipStream_t stream) {
    const float* sqscale     = (const float*)d_in[0];
    const float* exponents   = (const float*)d_in[1];
    const float* translation = (const float*)d_in[2];
    const float* rotation    = (const float*)d_in[3];
    const float* etas        = (const float*)d_in[4];
    const float* omegas      = (const float*)d_in[5];
    const float* offsets     = (const float*)d_in[6];
    const unsigned char* is_prune = (const unsigned char*)d_in[7];
    float* out = (float*)d_out;

    const int Ng = in_sizes[7];          // S*N points
    const int n_groups = Ng / 2;         // 2 points per thread
    const int block = 256;
    const int grid = (n_groups + block - 1) / block;

    superq_kernel<<<grid, block, 0, stream>>>(
        sqscale, exponents, translation, rotation,
        etas, omegas, offsets, is_prune, out, n_groups);
}